// Round 14
// baseline (2826.427 us; speedup 1.0000x reference)
//
#include <hip/hip_runtime.h>

#define BB 64
#define TT 512
#define HH 1024
#define OUTN 32000
#define NDOM 4              // 4 independent domains: 16 batch rows each
#define NCW 8               // col-WGs per domain, 128 cols each
#define NWG (NDOM * NCW)    // 32 workgroups (1 CU each)
#define NTH 512             // 8 waves; wave w owns 16 of the WG's 128 cols
#define SLOT (BB * HH * 2)  // 128 KB per ring slot
#define DSL 32768           // per-domain slice bytes (16 rows x 1024 x 2B)
#define FLAGS_BYTES 4096
#define HBUF_OFF FLAGS_BYTES
#define EMB_OFF (512 * 1024)
#define EMB_BYTES ((size_t)TT * BB * HH * 4)
// ws: [flags 4KB][ring of 3 slots x 128KB] ... [emb slab at 512KB]
// slot: [dom4][kb32][row16][col32] bf16; chunk = 16B = (row, 8 cols), one
// lane's dwordx4 (atomic unit); bit14 of chunk's first u16 = step phase
// (tanh => bit14==0). slot0,1 init 0x00; slot2 init 0x40 (R5 scheme).
// flags[dom*64 + cw*8 + w]: monotonic, plain sc1 store by the SAME wave that
// issued its 32 data-chunk stores (program order; tags catch rare misorder).

typedef __attribute__((ext_vector_type(8))) short s16x8;
typedef __attribute__((ext_vector_type(4))) float f32x4;
typedef __attribute__((ext_vector_type(4))) int i32x4;

static __device__ __forceinline__ unsigned short f2bf(float f) {
  union { float f; unsigned u; } a; a.f = f;
  unsigned r = a.u + 0x7fffu + ((a.u >> 16) & 1u);   // RNE
  return (unsigned short)(r >> 16);
}

static __device__ __forceinline__ float ftanh(float x) {
  float e = __expf(2.0f * x);
  return 1.0f - 2.0f * __builtin_amdgcn_rcpf(e + 1.0f);
}

#define WAITV(n)                                                           \
  do { asm volatile("s_waitcnt vmcnt(" #n ")" ::: "memory");               \
       __builtin_amdgcn_sched_barrier(0); } while (0)

// emb[t][b][h] = Wxh[x[b][t]][h] (f32) — streaming pre-gather (R9-proven)
__global__ __launch_bounds__(256) void emb_gather(
    const int* __restrict__ x, const float* __restrict__ Wxh,
    float* __restrict__ emb) {
  int t = blockIdx.x >> 3;
  int b0 = (blockIdx.x & 7) * 8;
  int wv = threadIdx.x >> 6, l = threadIdx.x & 63;
  #pragma unroll
  for (int rr = 0; rr < 2; ++rr) {
    int b = b0 + wv * 2 + rr;
    int tok = x[b * TT + t];
    const float4* src = (const float4*)(Wxh + (size_t)tok * HH);
    float4* dst = (float4*)(emb + ((size_t)t * BB + b) * HH);
    #pragma unroll
    for (int c = 0; c < 4; ++c) dst[c * 64 + l] = src[c * 64 + l];
  }
}

__global__ __launch_bounds__(NTH, 1) void rnn_persist(
    const int* __restrict__ x, const float* __restrict__ Wxh,
    const float* __restrict__ Whh_w, const float* __restrict__ Whh_b,
    unsigned* __restrict__ flags, char* __restrict__ hbuf,
    const float* __restrict__ embp, int use_emb) {
  const int g = blockIdx.x;
  const int dom = g >> 3;          // batch rows [16*dom, +16)
  const int cw = g & 7;            // cols [128*cw, +128)
  const int tid = threadIdx.x;
  const int w = tid >> 6;          // wave 0..7 -> cols [cw*128 + w*16, +16)
  const int l = tid & 63;
  const int lr = l & 15;
  const int lq = l >> 4;

  // double-buffered A slice (32 KB each) + wave-private epi + verify flags
  __shared__ __align__(16) unsigned short lds_a[2][16384];
  __shared__ __align__(16) unsigned short epi[8 * 256];
  __shared__ unsigned ldsbad[8];

  // ---- one-time B pack: wave's 16-col Whh^T slice -> 128 VGPRs/lane ----
  // B-frag (16x16x32): lane ln supplies col = base + (ln&15),
  // k = kb*32 + (ln>>4)*8 + j
  const int colb = cw * 128 + w * 16 + lr;
  s16x8 bb[32];
  #pragma unroll
  for (int kb = 0; kb < 32; ++kb) {
    const float4* p = (const float4*)(Whh_w + (size_t)colb * HH + kb * 32 + lq * 8);
    float4 a0 = p[0], a1 = p[1];
    union { unsigned short u[8]; s16x8 v; } pk;
    pk.u[0] = f2bf(a0.x); pk.u[1] = f2bf(a0.y);
    pk.u[2] = f2bf(a0.z); pk.u[3] = f2bf(a0.w);
    pk.u[4] = f2bf(a1.x); pk.u[5] = f2bf(a1.y);
    pk.u[6] = f2bf(a1.z); pk.u[7] = f2bf(a1.w);
    bb[kb] = pk.v;
  }
  const float bias = Whh_b[colb];

  // token rows (for no-emb fallback)
  int xrow[4], xv[4];
  #pragma unroll
  for (int i = 0; i < 4; ++i) {
    xrow[i] = (dom * 16 + lq * 4 + i) * TT;
    xv[i] = x[xrow[i]];
  }

  // emb register double-buffer
  float evc[4], evn[4];
  if (use_emb) {
    #pragma unroll
    for (int i = 0; i < 4; ++i)
      evc[i] = embp[((size_t)0 * BB + dom * 16 + lq * 4 + i) * HH + colb];
  }

  unsigned* flagsD = flags + dom * 64;
  // coop-load: lane handles chunks {tid + k*512}, byte addr = tid*16 + k*8192
  const unsigned vo0 = (unsigned)(tid * 16);
  const unsigned vo1 = vo0 + 8192, vo2 = vo0 + 16384, vo3 = vo0 + 24576;

  for (int s = 0; s < TT; ++s) {
    const char* hprev = hbuf + (s % 3) * SLOT + dom * DSL;
    char* hcur = hbuf + ((s + 1) % 3) * SLOT + dom * DSL;
    const unsigned want = ((unsigned)(s & 1)) << 14;
    const int bufsel = s & 1;

    if (!use_emb) {   // fallback gather (hides under poll)
      #pragma unroll
      for (int i = 0; i < 4; ++i) evc[i] = Wxh[(size_t)xv[i] * HH + colb];
    }

    // 1. poll: 64 per-wave flags of my domain (256 B per iteration)
    if (s > 0) {
      const unsigned* fp = flagsD + l;
      int guard = 0;
      unsigned fv;
      do {
        asm volatile("global_load_dword %0, %1, off sc1\n\t"
                     "s_waitcnt vmcnt(0)"
                     : "=v"(fv) : "v"(fp) : "memory");
        if (++guard > (1 << 17)) break;   // safety valve
      } while (!__all(fv >= (unsigned)s));
      __builtin_amdgcn_sched_barrier(0);
    }

    // 2. cooperative A-load: 4 x 16B per lane (32 KB per WG total),
    //    then emb[s+1] prefetch (4 trailing loads; vmcnt retires in order)
    i32x4 areg[4];
    asm volatile("global_load_dwordx4 %0, %1, %2 sc1"
                 : "=v"(areg[0]) : "v"(vo0), "s"(hprev) : "memory");
    asm volatile("global_load_dwordx4 %0, %1, %2 sc1"
                 : "=v"(areg[1]) : "v"(vo1), "s"(hprev) : "memory");
    asm volatile("global_load_dwordx4 %0, %1, %2 sc1"
                 : "=v"(areg[2]) : "v"(vo2), "s"(hprev) : "memory");
    asm volatile("global_load_dwordx4 %0, %1, %2 sc1"
                 : "=v"(areg[3]) : "v"(vo3), "s"(hprev) : "memory");
    if (use_emb) {
      int snext = (s + 1 < TT) ? (s + 1) : s;
      #pragma unroll
      for (int i = 0; i < 4; ++i) {
        const float* ep =
            embp + ((size_t)snext * BB + dom * 16 + lq * 4 + i) * HH + colb;
        asm volatile("global_load_dword %0, %1, off"
                     : "=v"(evn[i]) : "v"(ep) : "memory");
      }
    } else {
      int snext = (s + 1 < TT) ? (s + 1) : s;
      #pragma unroll
      for (int i = 0; i < 4; ++i) xv[i] = x[xrow[i] + snext];
    }
    WAITV(4);   // the 4 A-loads are the oldest -> done; emb trails

    // 3. verify tags + stage to LDS; WG-uniform retry on rare failure
    int gr = 0;
    for (;;) {
      unsigned bad = 0;
      #pragma unroll
      for (int k = 0; k < 4; ++k) {
        unsigned u0 = (unsigned)areg[k][0];
        bad |= (u0 ^ want) & 0x4000u;
        areg[k][0] = (int)(u0 & ~0x4000u);
        *reinterpret_cast<i32x4*>(&lds_a[bufsel][(tid + k * 512) * 8]) = areg[k];
      }
      if (l == 0) ldsbad[w] = (unsigned)__all(bad == 0);
      __syncthreads();
      unsigned allg = ldsbad[0] & ldsbad[1] & ldsbad[2] & ldsbad[3] &
                      ldsbad[4] & ldsbad[5] & ldsbad[6] & ldsbad[7];
      if (allg) break;
      if (++gr > (1 << 15)) break;   // never hard-wedge
      __syncthreads();
      asm volatile("global_load_dwordx4 %0, %1, %2 sc1"
                   : "=v"(areg[0]) : "v"(vo0), "s"(hprev) : "memory");
      asm volatile("global_load_dwordx4 %0, %1, %2 sc1"
                   : "=v"(areg[1]) : "v"(vo1), "s"(hprev) : "memory");
      asm volatile("global_load_dwordx4 %0, %1, %2 sc1"
                   : "=v"(areg[2]) : "v"(vo2), "s"(hprev) : "memory");
      asm volatile("global_load_dwordx4 %0, %1, %2 sc1"
                   : "=v"(areg[3]) : "v"(vo3), "s"(hprev) : "memory");
      asm volatile("s_waitcnt vmcnt(0)" ::: "memory");
      __builtin_amdgcn_sched_barrier(0);
    }

    // 4. 32 MFMA per wave: A from LDS, B from registers, 4 acc chains
    f32x4 ac[4];
    #pragma unroll
    for (int c = 0; c < 4; ++c) ac[c] = (f32x4){0.f, 0.f, 0.f, 0.f};
    #pragma unroll
    for (int kb = 0; kb < 32; ++kb) {
      s16x8 a = *reinterpret_cast<const s16x8*>(
          &lds_a[bufsel][kb * 512 + lr * 32 + lq * 8]);
      ac[kb & 3] = __builtin_amdgcn_mfma_f32_16x16x32_bf16(a, bb[kb], ac[kb & 3], 0, 0, 0);
    }
    f32x4 acc = (ac[0] + ac[1]) + (ac[2] + ac[3]);
    WAITV(0);   // emb[s+1] landed (hidden under verify+MFMA)

    // 5. epilogue (wave-private): C/D col=lane&15 (=lr), row=lq*4+i
    #pragma unroll
    for (int i = 0; i < 4; ++i) {
      float v = ftanh(acc[i] + evc[i] + bias);
      epi[w * 256 + (lq * 4 + i) * 16 + lr] = f2bf(v);
    }
    if (use_emb) {
      #pragma unroll
      for (int i = 0; i < 4; ++i) evc[i] = evn[i];
    }
    asm volatile("s_waitcnt lgkmcnt(0)" ::: "memory");
    __builtin_amdgcn_sched_barrier(0);

    // 6. wave stores its 32 chunks (16 rows x its 16 cols), phase-tagged,
    //    then its flag — same wave, program order (R5-proven ordering).
    if (l < 32) {
      int r = l >> 1, hf = l & 1;
      i32x4 v = *reinterpret_cast<const i32x4*>(&epi[w * 256 + r * 16 + hf * 8]);
      v[0] |= (int)(((unsigned)((s + 1) & 1)) << 14);
      int coff = w * 16 + hf * 8;            // col offset within WG's 128
      char* dst = hcur + (size_t)(cw * 4 + (coff >> 5)) * 1024 + r * 64 +
                  (coff & 31) * 2;
      asm volatile("global_store_dwordx4 %0, %1, off sc1"
                   :: "v"(dst), "v"(v) : "memory");
    }
    if (l == 0) {
      unsigned sv = (unsigned)(s + 1);
      asm volatile("global_store_dword %0, %1, off sc1"
                   :: "v"(flagsD + cw * 8 + w), "v"(sv) : "memory");
    }
  }
}

// out[64][32000] = h_final @ Why^T + Why_b; h_512 = slot 2 (512%3==2),
// phase (512&1)==0 -> clean. LDS-staged Why (R11-proven, ~30 us).
__global__ __launch_bounds__(256) void rnn_proj(
    const char* __restrict__ hfin, const float* __restrict__ Why_w,
    const float* __restrict__ Why_b, float* __restrict__ out) {
  const int tid = threadIdx.x;
  const int w = tid >> 6;          // wave w -> batch rows [16w, 16w+16)
  const int l = tid & 63;
  const int lr = l & 15;
  const int lq = l >> 4;
  const int nbase = blockIdx.x * 128;

  __shared__ __align__(16) unsigned short blds[8 * 64 * 8];  // 8 KB B-frags

  f32x4 acc[8];
  #pragma unroll
  for (int nt = 0; nt < 8; ++nt) acc[nt] = (f32x4){0.f, 0.f, 0.f, 0.f};

  const char* abase = hfin + (size_t)w * 32768 + lr * 64 + lq * 16;
  for (int kb = 0; kb < 32; ++kb) {
    #pragma unroll
    for (int h = 0; h < 2; ++h) {
      int e = tid + h * 256;
      int nt = e >> 6, ln = e & 63;
      int n = nbase + nt * 16 + (ln & 15);
      int k0 = kb * 32 + (ln >> 4) * 8;
      const float4* wp = (const float4*)(Why_w + (size_t)n * HH + k0);
      float4 w0 = wp[0];
      float4 w1 = wp[1];
      union { unsigned short u[8]; i32x4 v; } bbu;
      bbu.u[0] = f2bf(w0.x); bbu.u[1] = f2bf(w0.y);
      bbu.u[2] = f2bf(w0.z); bbu.u[3] = f2bf(w0.w);
      bbu.u[4] = f2bf(w1.x); bbu.u[5] = f2bf(w1.y);
      bbu.u[6] = f2bf(w1.z); bbu.u[7] = f2bf(w1.w);
      *reinterpret_cast<i32x4*>(&blds[(size_t)e * 8]) = bbu.v;
    }
    __syncthreads();
    s16x8 a = *reinterpret_cast<const s16x8*>(abase + kb * 1024);
    #pragma unroll
    for (int nt = 0; nt < 8; ++nt) {
      s16x8 b = *reinterpret_cast<const s16x8*>(&blds[(nt * 64 + l) * 8]);
      acc[nt] = __builtin_amdgcn_mfma_f32_16x16x32_bf16(a, b, acc[nt], 0, 0, 0);
    }
    __syncthreads();
  }
  #pragma unroll
  for (int nt = 0; nt < 8; ++nt) {
    int n = nbase + nt * 16 + lr;
    float bv = Why_b[n];
    #pragma unroll
    for (int i = 0; i < 4; ++i) {
      int b = w * 16 + lq * 4 + i;
      out[(size_t)b * OUTN + n] = acc[nt][i] + bv;
    }
  }
}

extern "C" void kernel_launch(void* const* d_in, const int* in_sizes, int n_in,
                              void* d_out, int out_size, void* d_ws, size_t ws_size,
                              hipStream_t stream) {
  const int* x = (const int*)d_in[0];
  const float* Wxh = (const float*)d_in[1];
  const float* Whh_w = (const float*)d_in[2];
  const float* Whh_b = (const float*)d_in[3];
  const float* Why_w = (const float*)d_in[4];
  const float* Why_b = (const float*)d_in[5];
  float* out = (float*)d_out;

  char* ws = (char*)d_ws;
  unsigned* flags = (unsigned*)d_ws;
  char* hbuf = ws + HBUF_OFF;
  float* emb = (float*)(ws + EMB_OFF);
  int use_emb = (ws_size >= EMB_OFF + EMB_BYTES) ? 1 : 0;

  // flags=0; slot0 = h_0 = zeros (phase0 valid); slot1 = 0x00 (!=phase1);
  // slot2 = 0x40 (bit14=1 != phase0). Re-done every call — deterministic.
  hipMemsetAsync(ws, 0x00, HBUF_OFF + 2 * SLOT, stream);
  hipMemsetAsync(hbuf + 2 * SLOT, 0x40, SLOT, stream);
  if (use_emb) emb_gather<<<TT * 8, 256, 0, stream>>>(x, Wxh, emb);
  rnn_persist<<<NWG, NTH, 0, stream>>>(x, Wxh, Whh_w, Whh_b, flags, hbuf,
                                       emb, use_emb);
  rnn_proj<<<OUTN / 128, 256, 0, stream>>>(hbuf + 2 * SLOT, Why_w, Why_b, out);
}